// Round 3
// baseline (539.106 us; speedup 1.0000x reference)
//
#include <hip/hip_runtime.h>
#include <hip/hip_bf16.h>

typedef __bf16 bf16;
typedef __bf16 bf16x4 __attribute__((ext_vector_type(4)));
typedef __bf16 bf16x8 __attribute__((ext_vector_type(8)));
typedef float  f32x4  __attribute__((ext_vector_type(4)));
typedef float  f32x16 __attribute__((ext_vector_type(16)));

#define DEVFN static __device__ __forceinline__

static constexpr int T_STEPS = 25;
static constexpr int BATCH   = 256;
static constexpr int MROWS   = T_STEPS * BATCH;  // 6400

// async global->LDS, 16B/lane; LDS base must be wave-uniform (HW adds lane*16).
DEVFN void llds16(const void* g, void* l) {
    __builtin_amdgcn_global_load_lds(
        (const __attribute__((address_space(1))) void*)g,
        (__attribute__((address_space(3))) void*)l, 16, 0, 0);
}

// ---------------------------------------------------------------------------
// Precision splits (unchanged, R1/R3/R4/R8-verified): G0/G1 weights and x need
// 3 bf16 planes; w2 needs 2. Spike margins ~1e-7 make all kept passes required.
DEVFN void split3_chunk(const float* src, bf16* p0, bf16* p1, bf16* p2, int i) {
    float4 v = *(const float4*)(src + i);
    float vv[4] = {v.x, v.y, v.z, v.w};
    bf16x4 a, b, c;
#pragma unroll
    for (int k = 0; k < 4; ++k) {
        bf16 h0 = (bf16)vv[k];
        float r1 = vv[k] - (float)h0;      // exact
        bf16 h1 = (bf16)r1;
        float r2 = r1 - (float)h1;         // exact
        a[k] = h0; b[k] = h1; c[k] = (bf16)r2;
    }
    *(bf16x4*)(p0 + i) = a;
    *(bf16x4*)(p1 + i) = b;
    *(bf16x4*)(p2 + i) = c;
}

DEVFN void split2_chunk(const float* src, bf16* p0, bf16* p1, int i) {
    float4 v = *(const float4*)(src + i);
    float vv[4] = {v.x, v.y, v.z, v.w};
    bf16x4 a, b;
#pragma unroll
    for (int k = 0; k < 4; ++k) {
        bf16 h0 = (bf16)vv[k];
        a[k] = h0; b[k] = (bf16)(vv[k] - (float)h0);
    }
    *(bf16x4*)(p0 + i) = a;
    *(bf16x4*)(p1 + i) = b;
}

static constexpr int SB_W0 = 2048;
static constexpr int SB_W1 = 4096;
static constexpr int SB_W2 = 2048;
static constexpr int SB_X  = 6400;

__global__ void split_all(const float* __restrict__ w0, bf16* w0p0, bf16* w0p1, bf16* w0p2,
                          const float* __restrict__ w1, bf16* w1p0, bf16* w1p1, bf16* w1p2,
                          const float* __restrict__ w2, bf16* w2p0, bf16* w2p1,
                          const float* __restrict__ x,  bf16* xp0,  bf16* xp1,  bf16* xp2) {
    int b = blockIdx.x;
    if (b < SB_W0) {
        split3_chunk(w0, w0p0, w0p1, w0p2, b * 1024 + threadIdx.x * 4);
    } else if (b < SB_W0 + SB_W1) {
        split3_chunk(w1, w1p0, w1p1, w1p2, (b - SB_W0) * 1024 + threadIdx.x * 4);
    } else if (b < SB_W0 + SB_W1 + SB_W2) {
        split2_chunk(w2, w2p0, w2p1, (b - SB_W0 - SB_W1) * 1024 + threadIdx.x * 4);
    } else {
        split3_chunk(x, xp0, xp1, xp2, (b - SB_W0 - SB_W1 - SB_W2) * 1024 + threadIdx.x * 4);
    }
}

// ---------------------------------------------------------------------------
// R3: 32x32x16 MFMA (2382-2495 TF ubench vs 2075 for 16x16x32 -> +20% pipe,
// half the instruction count). Per wave 64x64 = 2x2 tiles of 32x32; per pass
// 8 MFMAs + 4 ds_read_b128 (same LDS bytes). Swizzle algebra unchanged:
// row = wrow + i*32 + (lane&31) -> ((row>>1)&3) == ((lane>>1)&3), same key
// as the 16x16 layout, so stage_plane and the 0-conflict pattern carry over.
// C/D mapping (m74/m101-verified): col=lane&31, row=(reg&3)+8*(reg>>2)+4*(lane>>5).
// Schedule unchanged from R2: single __syncthreads per K-tile, prefetch
// distance = 1 full tile body (flight >= ~4000 cyc >> 900 cyc HBM latency).
// Residency note: dual-acc (128 regs) forces 2 waves/SIMD -> 1 block/CU; LDS
// sizing is irrelevant to occupancy, so buffers stay as-is.

struct TileCtx { int t, lane, wm, wn, bm, bn, fr, fk0, fk1, cr, cc; };

DEVFN TileCtx make_ctx512() {
    TileCtx x;
    x.t = threadIdx.x; x.lane = x.t & 63;
    int wv = x.t >> 6;                       // 0..7
    x.wm = (wv >> 1) * 64;                   // 0,64,128,192 within BM=256
    x.wn = (wv & 1) * 64;                    // 0,64       within BN=128
    x.bm = blockIdx.x * 256; x.bn = blockIdx.y * 128;
    x.fr = x.lane & 31;                      // A/B fragment row (M or N index)
    int h  = x.lane >> 5;                    // k-half: 8 contiguous k per lane
    int sw = (x.lane >> 1) & 3;              // row-XOR swizzle key ((row>>1)&3)
    x.fk0 = ((0 + h) ^ sw) * 16;             // kk=0: 16B chunk within 64B row
    x.fk1 = ((2 + h) ^ sw) * 16;             // kk=1
    x.cr = 4 * h;                            // C/D row base adder 4*(lane>>5)
    x.cc = x.lane & 31;                      // C/D col
    return x;
}

// stage a ROWSx32 bf16 plane into LDS, swizzled: LDS slot (r,q) holds global
// chunk q ^ ((r>>1)&3); dest is lane-linear (global_load_lds requirement),
// source address carries the swizzle (rule #21: both-sides-or-neither).
template <int ROWS>
DEVFN void stage(const bf16* g, bf16* s, int base_row, int K, int k0, int t) {
#pragma unroll
    for (int r = 0; r < ROWS / 128; ++r) {
        int c   = t + r * 512;               // 16B chunk index
        int row = c >> 2;
        int kc  = (((c & 3) ^ ((c >> 3) & 3))) * 8;
        llds16(g + (size_t)(base_row + row) * K + k0 + kc,
               (bf16*)((char*)s + (c >> 6) * 1024));
    }
}

// swizzled LDS fragment read for 32x32x16: f[kk][i] covers rows wrow+i*32..+31,
// k = kk*16 + (lane>>5)*8 .. +7. One ds_read_b128 each.
DEVFN void frag22(bf16x8 (&f)[2][2], const bf16* s, int wrow, const TileCtx& x) {
#pragma unroll
    for (int i = 0; i < 2; ++i) {
        const char* rowp = (const char*)s + (wrow + i * 32 + x.fr) * 64;
        f[0][i] = *(const bf16x8*)(rowp + x.fk0);
        f[1][i] = *(const bf16x8*)(rowp + x.fk1);
    }
}

DEVFN void mfma8(f32x16 (&acc)[2][2], const bf16x8 (&a)[2][2], const bf16x8 (&b)[2][2]) {
    __builtin_amdgcn_s_setprio(1);
#pragma unroll
    for (int kk = 0; kk < 2; ++kk)
#pragma unroll
        for (int i = 0; i < 2; ++i)
#pragma unroll
            for (int j = 0; j < 2; ++j)
                acc[i][j] = __builtin_amdgcn_mfma_f32_32x32x16_bf16(
                    a[kk][i], b[kk][j], acc[i][j], 0, 0, 0);
    __builtin_amdgcn_s_setprio(0);
}

// fp64 merge: accM + accS + bias summed in double, single round to f32.
DEVFN void epilogue(const f32x16 (&accM)[2][2], const f32x16 (&accS)[2][2],
                    const float* bias, float* C, int N, const TileCtx& x) {
#pragma unroll
    for (int j = 0; j < 2; ++j) {
        int col   = x.bn + x.wn + j * 32 + x.cc;
        double bv = (double)bias[col];
#pragma unroll
        for (int i = 0; i < 2; ++i) {
            int rbase = x.bm + x.wm + i * 32 + x.cr;
#pragma unroll
            for (int r = 0; r < 16; ++r) {
                int row = rbase + (r & 3) + 8 * (r >> 2);
                double v = (double)accM[i][j][r] + (double)accS[i][j][r] + bv;
                C[(size_t)row * N + col] = (float)v;
            }
        }
    }
}

// MODE 0: L0 (3 A planes, 3 B planes, 6 passes)
// MODE 1: L1 (1 A plane,  3 B planes, 3 passes)
// MODE 2: L2 (1 A plane,  2 B planes, 2 passes)
template <int MODE>
__global__ __launch_bounds__(512, 2)
void gemm_ph(const bf16* __restrict__ A0, const bf16* __restrict__ A1,
             const bf16* __restrict__ A2, const bf16* __restrict__ B0,
             const bf16* __restrict__ B1, const bf16* __restrict__ B2,
             const float* __restrict__ bias, float* __restrict__ C,
             int M, int N, int K) {
    constexpr int NA  = (MODE == 0) ? 3 : 1;
    constexpr int NB  = (MODE == 2) ? 2 : 3;
    constexpr int APL = 256 * 32;            // A plane elems (16 KiB)
    constexpr int BPL = 128 * 32;            // B plane elems ( 8 KiB)
    constexpr int BUF = NA * APL + NB * BPL;
    __shared__ __align__(1024) bf16 lds[2 * BUF];   // MODE0:144K  1:80K  2:64K

    TileCtx x = make_ctx512();
    f32x16 accM[2][2] = {}, accS[2][2] = {};

    auto pA = [&](int p, int i) { return lds + p * BUF + i * APL; };
    auto pB = [&](int p, int i) { return lds + p * BUF + NA * APL + i * BPL; };

    auto stage_all = [&](int p, int k0) {
        stage<256>(A0, pA(p, 0), x.bm, K, k0, x.t);
        if constexpr (MODE == 0) {
            stage<256>(A1, pA(p, 1), x.bm, K, k0, x.t);
            stage<256>(A2, pA(p, 2), x.bm, K, k0, x.t);
        }
        stage<128>(B0, pB(p, 0), x.bn, K, k0, x.t);
        stage<128>(B1, pB(p, 1), x.bn, K, k0, x.t);
        if constexpr (NB == 3) stage<128>(B2, pB(p, 2), x.bn, K, k0, x.t);
    };

    // prologue: tile 0 into buf 0; the one full-latency drain of the kernel
    stage_all(0, 0);
    __syncthreads();

    const int NT = K / 32;
    int p = 0;
    for (int tt = 0; tt < NT; ++tt, p ^= 1) {
        // prefetch tile t+1 into the other buffer (flight = rest of this body)
        if (tt + 1 < NT) stage_all(p ^ 1, (tt + 1) * 32);

        bf16x8 a[2][2], b0f[2][2], b1f[2][2], b2f[2][2];
        if constexpr (MODE == 0) {
            frag22(a,   pA(p, 0), x.wm, x);
            frag22(b0f, pB(p, 0), x.wn, x);
            mfma8(accM, a, b0f);
            frag22(b1f, pB(p, 1), x.wn, x);
            mfma8(accS, a, b1f);
            frag22(b2f, pB(p, 2), x.wn, x);
            mfma8(accS, a, b2f);
            frag22(a, pA(p, 1), x.wm, x);    // a1
            mfma8(accS, a, b0f);
            mfma8(accS, a, b1f);
            frag22(a, pA(p, 2), x.wm, x);    // a2
            mfma8(accS, a, b0f);
        } else if constexpr (MODE == 1) {
            frag22(a,   pA(p, 0), x.wm, x);
            frag22(b0f, pB(p, 0), x.wn, x);
            mfma8(accM, a, b0f);
            frag22(b1f, pB(p, 1), x.wn, x);
            mfma8(accS, a, b1f);
            frag22(b2f, pB(p, 2), x.wn, x);
            mfma8(accS, a, b2f);
        } else {
            frag22(a,   pA(p, 0), x.wm, x);
            frag22(b0f, pB(p, 0), x.wn, x);
            mfma8(accM, a, b0f);
            frag22(b1f, pB(p, 1), x.wn, x);
            mfma8(accS, a, b1f);
        }
        // single per-tile barrier: gates buf(p^1) visibility for next tile and
        // protects buf(p) against next tile's stages (readers are done here).
        __syncthreads();
    }
    epilogue(accM, accS, bias, C, N, x);
}

// ---------------------------------------------------------------------------
// LIF scans — fp64 recurrence (R4-verified: kills the f32 drift flips).
template <int F>
__global__ void lif_hidden(const float* __restrict__ cur, bf16* __restrict__ spk) {
    const int tid = blockIdx.x * 256 + threadIdx.x;  // b*F + f
    double m = 0.0;
    size_t off = tid;
#pragma unroll
    for (int t = 0; t < T_STEPS; ++t) {
        m = 0.9 * m + (double)cur[off];
        bool s = (m - 1.0) > 0.0;
        spk[off] = (bf16)(s ? 1.0f : 0.0f);
        if (s) m -= 1.0;
        off += (size_t)BATCH * F;
    }
}

__global__ void lif_out(const float* __restrict__ cur, float* __restrict__ out) {
    const int tid = blockIdx.x * 256 + threadIdx.x;  // b*1024 + f
    double m = 0.0;
    size_t off = tid;
#pragma unroll
    for (int t = 0; t < T_STEPS; ++t) {
        m = 0.9 * m + (double)cur[off];
        bool s = (m - 1.0) > 0.0;
        out[off] = s ? 1.0f : 0.0f;
        if (s) m -= 1.0;
        off += (size_t)BATCH * 1024;
    }
    out[(size_t)T_STEPS * BATCH * 1024 + tid] = (float)m;  // final membrane (output 1)
}

// ---------------------------------------------------------------------------
extern "C" void kernel_launch(void* const* d_in, const int* in_sizes, int n_in,
                              void* d_out, int out_size, void* d_ws, size_t ws_size,
                              hipStream_t stream) {
    const float* xin = (const float*)d_in[0];
    const float* w0  = (const float*)d_in[1];
    const float* b0  = (const float*)d_in[2];
    const float* w1  = (const float*)d_in[3];
    const float* b1  = (const float*)d_in[4];
    const float* w2  = (const float*)d_in[5];
    const float* b2  = (const float*)d_in[6];
    float* out = (float*)d_out;

    constexpr size_t NW0 = 2048 * 1024;
    constexpr size_t NW1 = 2048 * 2048;
    constexpr size_t NW2 = 1024 * 2048;
    constexpr size_t NX  = (size_t)MROWS * 1024;  // 6,553,600
    constexpr size_t NH  = (size_t)MROWS * 2048;  // 13,107,200

    char* ws = (char*)d_ws;
    size_t off = 0;
    auto carve = [&](size_t bytes) { char* p = ws + off; off += bytes; return p; };

    // long-lived planes
    bf16* w1p0 = (bf16*)carve(NW1 * 2);
    bf16* w1p1 = (bf16*)carve(NW1 * 2);
    bf16* w1p2 = (bf16*)carve(NW1 * 2);
    bf16* w2p0 = (bf16*)carve(NW2 * 2);
    bf16* w2p1 = (bf16*)carve(NW2 * 2);
    // pool: w0 planes + x planes live only until G0; s0/s1 overlay afterwards
    char* pool = carve(2 * NH * 2);          // 52,428,800 B
    bf16* w0p0 = (bf16*)pool;
    bf16* w0p1 = w0p0 + NW0;
    bf16* w0p2 = w0p1 + NW0;
    bf16* xp0  = w0p2 + NW0;
    bf16* xp1  = xp0 + NX;
    bf16* xp2  = xp1 + NX;                   // ends at pool + 51,904,512
    bf16* s0   = (bf16*)pool;                // written after G0 consumed w0/x
    bf16* s1   = s0 + NH;                    // written after G1 consumed s0
    float* cur = (float*)carve(NH * 4);
    if (ws_size < off) return;               // 138,412,032 B total

    // 1) fused precision splits (one launch)
    split_all<<<SB_W0 + SB_W1 + SB_W2 + SB_X, 256, 0, stream>>>(
        w0, w0p0, w0p1, w0p2, w1, w1p0, w1p1, w1p2,
        w2, w2p0, w2p1, xin, xp0, xp1, xp2);

    // 2) layer 0: cur0 = x @ W0^T + b0 (M=6400,N=2048,K=1024; 6-pass dual-acc)
    gemm_ph<0><<<dim3(25, 16), 512, 0, stream>>>(xp0, xp1, xp2, w0p0, w0p1, w0p2,
                                                 b0, cur, MROWS, 2048, 1024);
    lif_hidden<2048><<<(BATCH * 2048) / 256, 256, 0, stream>>>(cur, s0);

    // 3) layer 1: cur1 = s0 @ W1^T + b1 (K=2048; 3-pass dual-acc)
    gemm_ph<1><<<dim3(25, 16), 512, 0, stream>>>(s0, nullptr, nullptr, w1p0, w1p1, w1p2,
                                                 b1, cur, MROWS, 2048, 2048);
    lif_hidden<2048><<<(BATCH * 2048) / 256, 256, 0, stream>>>(cur, s1);

    // 4) layer 2: cur2 = s1 @ W2^T + b2 (N=1024; 2-pass dual-acc)
    gemm_ph<2><<<dim3(25, 8), 512, 0, stream>>>(s1, nullptr, nullptr, w2p0, w2p1, nullptr,
                                                b2, cur, MROWS, 1024, 2048);
    lif_out<<<(BATCH * 1024) / 256, 256, 0, stream>>>(cur, out);
}

// Round 4
// 470.154 us; speedup vs baseline: 1.1467x; 1.1467x over previous
//
#include <hip/hip_runtime.h>
#include <hip/hip_bf16.h>

typedef __bf16 bf16;
typedef __bf16 bf16x4 __attribute__((ext_vector_type(4)));
typedef __bf16 bf16x8 __attribute__((ext_vector_type(8)));
typedef float  f32x4  __attribute__((ext_vector_type(4)));

#define DEVFN static __device__ __forceinline__

static constexpr int T_STEPS = 25;
static constexpr int BATCH   = 256;
static constexpr int MROWS   = T_STEPS * BATCH;  // 6400

// async global->LDS, 16B/lane; LDS base must be wave-uniform (HW adds lane*16).
DEVFN void llds16(const void* g, void* l) {
    __builtin_amdgcn_global_load_lds(
        (const __attribute__((address_space(1))) void*)g,
        (__attribute__((address_space(3))) void*)l, 16, 0, 0);
}

// ---------------------------------------------------------------------------
// Precision splits (unchanged, verified): G0/G1 weights and x need 3 bf16
// planes; w2 needs 2. Spike margins ~1e-7 make all kept passes required.
DEVFN void split3_chunk(const float* src, bf16* p0, bf16* p1, bf16* p2, int i) {
    float4 v = *(const float4*)(src + i);
    float vv[4] = {v.x, v.y, v.z, v.w};
    bf16x4 a, b, c;
#pragma unroll
    for (int k = 0; k < 4; ++k) {
        bf16 h0 = (bf16)vv[k];
        float r1 = vv[k] - (float)h0;      // exact
        bf16 h1 = (bf16)r1;
        float r2 = r1 - (float)h1;         // exact
        a[k] = h0; b[k] = h1; c[k] = (bf16)r2;
    }
    *(bf16x4*)(p0 + i) = a;
    *(bf16x4*)(p1 + i) = b;
    *(bf16x4*)(p2 + i) = c;
}

DEVFN void split2_chunk(const float* src, bf16* p0, bf16* p1, int i) {
    float4 v = *(const float4*)(src + i);
    float vv[4] = {v.x, v.y, v.z, v.w};
    bf16x4 a, b;
#pragma unroll
    for (int k = 0; k < 4; ++k) {
        bf16 h0 = (bf16)vv[k];
        a[k] = h0; b[k] = (bf16)(vv[k] - (float)h0);
    }
    *(bf16x4*)(p0 + i) = a;
    *(bf16x4*)(p1 + i) = b;
}

static constexpr int SB_W0 = 2048;
static constexpr int SB_W1 = 4096;
static constexpr int SB_W2 = 2048;
static constexpr int SB_X  = 6400;

__global__ void split_all(const float* __restrict__ w0, bf16* w0p0, bf16* w0p1, bf16* w0p2,
                          const float* __restrict__ w1, bf16* w1p0, bf16* w1p1, bf16* w1p2,
                          const float* __restrict__ w2, bf16* w2p0, bf16* w2p1,
                          const float* __restrict__ x,  bf16* xp0,  bf16* xp1,  bf16* xp2) {
    int b = blockIdx.x;
    if (b < SB_W0) {
        split3_chunk(w0, w0p0, w0p1, w0p2, b * 1024 + threadIdx.x * 4);
    } else if (b < SB_W0 + SB_W1) {
        split3_chunk(w1, w1p0, w1p1, w1p2, (b - SB_W0) * 1024 + threadIdx.x * 4);
    } else if (b < SB_W0 + SB_W1 + SB_W2) {
        split2_chunk(w2, w2p0, w2p1, (b - SB_W0 - SB_W1) * 1024 + threadIdx.x * 4);
    } else {
        split3_chunk(x, xp0, xp1, xp2, (b - SB_W0 - SB_W1 - SB_W2) * 1024 + threadIdx.x * 4);
    }
}

// ---------------------------------------------------------------------------
// R4: back to the verified 16x16x32 MFMA + R2 schedule (single __syncthreads
// per K-tile, 1-tile-body prefetch flight). R3 post-mortem: the wall is
// per-tile overhead (~2200 cyc/body vs 1860 MFMA), NOT MFMA throughput; the
// 32x32 shape bought nothing and its read pattern cost 9.8M conflict cycles.
// This round: amortize the overhead by doubling BK where LDS fits:
//   MODE1 (L1): BK=64, LDS 2x(32K+3x16K)=160KiB (AITER precedent), 32 bodies.
//   MODE2 (L2): BK=64, LDS 128KiB, 32 bodies.
//   MODE0 (L0): BK=32 unchanged (6 planes can't fit BK=64).
// BK=64 swizzle: rows are 128B = 8 chunks; slot = src_chunk ^ (row&7).
// Read: lane group g=lane>>4 reads global chunk kh*4+g of row fr=lane&15 at
// slot (kh*4+g)^(lane&7): every 8 consecutive lanes covers all 8 bank-quads;
// worst aliasing 2 lanes/slot on different rows (2-way = free). Mirrors the
// verified BK=32 pattern's structure.
// Also removed s_setprio around MFMA (m190: negative on lockstep schedules).

struct TileCtx { int t, lane, wm, wn, bm, bn, fr, fkS, fk64a, fk64b, cr, cc; };

DEVFN TileCtx make_ctx512() {
    TileCtx x;
    x.t = threadIdx.x; x.lane = x.t & 63;
    int wv = x.t >> 6;                       // 0..7
    x.wm = (wv >> 1) * 64;                   // 0,64,128,192 within BM=256
    x.wn = (wv & 1) * 64;                    // 0,64       within BN=128
    x.bm = blockIdx.x * 256; x.bn = blockIdx.y * 128;
    x.fr  = x.lane & 15;
    int g = x.lane >> 4;                     // k-chunk group
    x.fkS   = (g ^ ((x.lane >> 1) & 3)) * 16;        // BK=32 swizzled chunk, bytes
    x.fk64a = ((0 * 4 + g) ^ (x.lane & 7)) * 16;     // BK=64, k-half 0
    x.fk64b = ((1 * 4 + g) ^ (x.lane & 7)) * 16;     // BK=64, k-half 1
    x.cr = (x.lane >> 4) * 4; x.cc = x.lane & 15;
    return x;
}

// stage a ROWSxBK bf16 plane into LDS, swizzled; dest lane-linear
// (global_load_lds requirement), source address carries the swizzle.
template <int ROWS, int BK>
DEVFN void stageP(const bf16* g, bf16* s, int base_row, int K, int k0, int t) {
    constexpr int CPR  = BK / 8;             // 16B chunks per row (4 or 8)
    constexpr int ITER = ROWS * CPR / 512;
#pragma unroll
    for (int r = 0; r < ITER; ++r) {
        int c    = t + r * 512;              // 16B chunk index
        int row  = c / CPR;
        int slot = c % CPR;
        int src  = (BK == 32) ? (slot ^ ((row >> 1) & 3))
                              : (slot ^ (row & 7));
        llds16(g + (size_t)(base_row + row) * K + k0 + src * 8,
               (bf16*)((char*)s + (c >> 6) * 1024));
    }
}

// swizzled LDS fragment read; row stride = 2*BK bytes
template <int BK>
DEVFN void frag4(bf16x8* f, const bf16* s, int wrow, int fr, int fkS) {
#pragma unroll
    for (int i = 0; i < 4; ++i)
        f[i] = *(const bf16x8*)((const char*)s + (wrow + i * 16 + fr) * (2 * BK) + fkS);
}

DEVFN void mfma16(f32x4 (&acc)[4][4], const bf16x8* a, const bf16x8* b) {
#pragma unroll
    for (int i = 0; i < 4; ++i)
#pragma unroll
        for (int j = 0; j < 4; ++j)
            acc[i][j] = __builtin_amdgcn_mfma_f32_16x16x32_bf16(a[i], b[j], acc[i][j], 0, 0, 0);
}

// fp64 merge: accM + accS + bias summed in double, single round to f32.
DEVFN void epilogue(const f32x4 (&accM)[4][4], const f32x4 (&accS)[4][4],
                    const float* bias, float* C, int N, const TileCtx& x) {
#pragma unroll
    for (int j = 0; j < 4; ++j) {
        int col   = x.bn + x.wn + j * 16 + x.cc;
        double bv = (double)bias[col];
#pragma unroll
        for (int i = 0; i < 4; ++i) {
            int row0 = x.bm + x.wm + i * 16 + x.cr;
#pragma unroll
            for (int r = 0; r < 4; ++r) {
                double v = (double)accM[i][j][r] + (double)accS[i][j][r] + bv;
                C[(size_t)(row0 + r) * N + col] = (float)v;
            }
        }
    }
}

// MODE 0: L0 (3 A planes, 3 B planes, 6 passes, BK=32)
// MODE 1: L1 (1 A plane,  3 B planes, 3 passes, BK=64)
// MODE 2: L2 (1 A plane,  2 B planes, 2 passes, BK=64)
template <int MODE>
__global__ __launch_bounds__(512, 2)
void gemm_ph(const bf16* __restrict__ A0, const bf16* __restrict__ A1,
             const bf16* __restrict__ A2, const bf16* __restrict__ B0,
             const bf16* __restrict__ B1, const bf16* __restrict__ B2,
             const float* __restrict__ bias, float* __restrict__ C,
             int M, int N, int K) {
    constexpr int BK  = (MODE == 0) ? 32 : 64;
    constexpr int NA  = (MODE == 0) ? 3 : 1;
    constexpr int NB  = (MODE == 2) ? 2 : 3;
    constexpr int APL = 256 * BK;            // A plane elems
    constexpr int BPL = 128 * BK;            // B plane elems
    constexpr int BUF = NA * APL + NB * BPL;
    __shared__ __align__(1024) bf16 lds[2 * BUF];   // MODE0:144K 1:160K 2:128K

    TileCtx x = make_ctx512();
    f32x4 accM[4][4] = {}, accS[4][4] = {};

    auto pA = [&](int p, int i) { return lds + p * BUF + i * APL; };
    auto pB = [&](int p, int i) { return lds + p * BUF + NA * APL + i * BPL; };

    auto stage_all = [&](int p, int k0) {
        stageP<256, BK>(A0, pA(p, 0), x.bm, K, k0, x.t);
        if constexpr (MODE == 0) {
            stageP<256, BK>(A1, pA(p, 1), x.bm, K, k0, x.t);
            stageP<256, BK>(A2, pA(p, 2), x.bm, K, k0, x.t);
        }
        stageP<128, BK>(B0, pB(p, 0), x.bn, K, k0, x.t);
        stageP<128, BK>(B1, pB(p, 1), x.bn, K, k0, x.t);
        if constexpr (NB == 3) stageP<128, BK>(B2, pB(p, 2), x.bn, K, k0, x.t);
    };

    // prologue: tile 0 into buf 0; the one full-latency drain of the kernel
    stage_all(0, 0);
    __syncthreads();

    const int NT = K / BK;
    int p = 0;
    for (int tt = 0; tt < NT; ++tt, p ^= 1) {
        // prefetch tile t+1 into the other buffer (flight = rest of this body)
        if (tt + 1 < NT) stage_all(p ^ 1, (tt + 1) * BK);

        bf16x8 a[4], b0f[4], b1f[4], b2f[4];
        if constexpr (MODE == 0) {
            frag4<32>(a,   pA(p, 0), x.wm, x.fr, x.fkS);
            frag4<32>(b0f, pB(p, 0), x.wn, x.fr, x.fkS);
            mfma16(accM, a, b0f);
            frag4<32>(b1f, pB(p, 1), x.wn, x.fr, x.fkS);
            mfma16(accS, a, b1f);
            frag4<32>(b2f, pB(p, 2), x.wn, x.fr, x.fkS);
            mfma16(accS, a, b2f);
            frag4<32>(a, pA(p, 1), x.wm, x.fr, x.fkS);   // a1
            mfma16(accS, a, b0f);
            mfma16(accS, a, b1f);
            frag4<32>(a, pA(p, 2), x.wm, x.fr, x.fkS);   // a2
            mfma16(accS, a, b0f);
        } else {
            // two k-halves processed sequentially: register pressure == BK=32 body
#pragma unroll
            for (int kh = 0; kh < 2; ++kh) {
                const int fk = kh ? x.fk64b : x.fk64a;
                frag4<64>(a,   pA(p, 0), x.wm, x.fr, fk);
                frag4<64>(b0f, pB(p, 0), x.wn, x.fr, fk);
                mfma16(accM, a, b0f);
                frag4<64>(b1f, pB(p, 1), x.wn, x.fr, fk);
                mfma16(accS, a, b1f);
                if constexpr (NB == 3) {
                    frag4<64>(b2f, pB(p, 2), x.wn, x.fr, fk);
                    mfma16(accS, a, b2f);
                }
            }
        }
        // single per-tile barrier: gates buf(p^1) visibility for next tile and
        // protects buf(p) against next tile's stages (readers are done here).
        __syncthreads();
    }
    epilogue(accM, accS, bias, C, N, x);
}

// ---------------------------------------------------------------------------
// LIF scans — fp64 recurrence (verified: kills the f32 drift flips).
template <int F>
__global__ void lif_hidden(const float* __restrict__ cur, bf16* __restrict__ spk) {
    const int tid = blockIdx.x * 256 + threadIdx.x;  // b*F + f
    double m = 0.0;
    size_t off = tid;
#pragma unroll
    for (int t = 0; t < T_STEPS; ++t) {
        m = 0.9 * m + (double)cur[off];
        bool s = (m - 1.0) > 0.0;
        spk[off] = (bf16)(s ? 1.0f : 0.0f);
        if (s) m -= 1.0;
        off += (size_t)BATCH * F;
    }
}

__global__ void lif_out(const float* __restrict__ cur, float* __restrict__ out) {
    const int tid = blockIdx.x * 256 + threadIdx.x;  // b*1024 + f
    double m = 0.0;
    size_t off = tid;
#pragma unroll
    for (int t = 0; t < T_STEPS; ++t) {
        m = 0.9 * m + (double)cur[off];
        bool s = (m - 1.0) > 0.0;
        out[off] = s ? 1.0f : 0.0f;
        if (s) m -= 1.0;
        off += (size_t)BATCH * 1024;
    }
    out[(size_t)T_STEPS * BATCH * 1024 + tid] = (float)m;  // final membrane (output 1)
}

// ---------------------------------------------------------------------------
extern "C" void kernel_launch(void* const* d_in, const int* in_sizes, int n_in,
                              void* d_out, int out_size, void* d_ws, size_t ws_size,
                              hipStream_t stream) {
    const float* xin = (const float*)d_in[0];
    const float* w0  = (const float*)d_in[1];
    const float* b0  = (const float*)d_in[2];
    const float* w1  = (const float*)d_in[3];
    const float* b1  = (const float*)d_in[4];
    const float* w2  = (const float*)d_in[5];
    const float* b2  = (const float*)d_in[6];
    float* out = (float*)d_out;

    constexpr size_t NW0 = 2048 * 1024;
    constexpr size_t NW1 = 2048 * 2048;
    constexpr size_t NW2 = 1024 * 2048;
    constexpr size_t NX  = (size_t)MROWS * 1024;  // 6,553,600
    constexpr size_t NH  = (size_t)MROWS * 2048;  // 13,107,200

    char* ws = (char*)d_ws;
    size_t off = 0;
    auto carve = [&](size_t bytes) { char* p = ws + off; off += bytes; return p; };

    // long-lived planes
    bf16* w1p0 = (bf16*)carve(NW1 * 2);
    bf16* w1p1 = (bf16*)carve(NW1 * 2);
    bf16* w1p2 = (bf16*)carve(NW1 * 2);
    bf16* w2p0 = (bf16*)carve(NW2 * 2);
    bf16* w2p1 = (bf16*)carve(NW2 * 2);
    // pool: w0 planes + x planes live only until G0; s0/s1 overlay afterwards
    char* pool = carve(2 * NH * 2);          // 52,428,800 B
    bf16* w0p0 = (bf16*)pool;
    bf16* w0p1 = w0p0 + NW0;
    bf16* w0p2 = w0p1 + NW0;
    bf16* xp0  = w0p2 + NW0;
    bf16* xp1  = xp0 + NX;
    bf16* xp2  = xp1 + NX;                   // ends at pool + 51,904,512
    bf16* s0   = (bf16*)pool;                // written after G0 consumed w0/x
    bf16* s1   = s0 + NH;                    // written after G1 consumed s0
    float* cur = (float*)carve(NH * 4);
    if (ws_size < off) return;               // 138,412,032 B total

    // 1) fused precision splits (one launch)
    split_all<<<SB_W0 + SB_W1 + SB_W2 + SB_X, 256, 0, stream>>>(
        w0, w0p0, w0p1, w0p2, w1, w1p0, w1p1, w1p2,
        w2, w2p0, w2p1, xin, xp0, xp1, xp2);

    // 2) layer 0: cur0 = x @ W0^T + b0 (M=6400,N=2048,K=1024; 6-pass dual-acc)
    gemm_ph<0><<<dim3(25, 16), 512, 0, stream>>>(xp0, xp1, xp2, w0p0, w0p1, w0p2,
                                                 b0, cur, MROWS, 2048, 1024);
    lif_hidden<2048><<<(BATCH * 2048) / 256, 256, 0, stream>>>(cur, s0);

    // 3) layer 1: cur1 = s0 @ W1^T + b1 (K=2048; 3-pass dual-acc, BK=64)
    gemm_ph<1><<<dim3(25, 16), 512, 0, stream>>>(s0, nullptr, nullptr, w1p0, w1p1, w1p2,
                                                 b1, cur, MROWS, 2048, 2048);
    lif_hidden<2048><<<(BATCH * 2048) / 256, 256, 0, stream>>>(cur, s1);

    // 4) layer 2: cur2 = s1 @ W2^T + b2 (N=1024; 2-pass dual-acc, BK=64)
    gemm_ph<2><<<dim3(25, 8), 512, 0, stream>>>(s1, nullptr, nullptr, w2p0, w2p1, nullptr,
                                                b2, cur, MROWS, 1024, 2048);
    lif_out<<<(BATCH * 1024) / 256, 256, 0, stream>>>(cur, out);
}

// Round 5
// 465.186 us; speedup vs baseline: 1.1589x; 1.0107x over previous
//
#include <hip/hip_runtime.h>
#include <hip/hip_bf16.h>

typedef __bf16 bf16;
typedef __bf16 bf16x4 __attribute__((ext_vector_type(4)));
typedef __bf16 bf16x8 __attribute__((ext_vector_type(8)));
typedef float  f32x4  __attribute__((ext_vector_type(4)));

#define DEVFN static __device__ __forceinline__

static constexpr int T_STEPS = 25;
static constexpr int BATCH   = 256;
static constexpr int MROWS   = T_STEPS * BATCH;  // 6400

// async global->LDS, 16B/lane; LDS base must be wave-uniform (HW adds lane*16).
DEVFN void llds16(const void* g, void* l) {
    __builtin_amdgcn_global_load_lds(
        (const __attribute__((address_space(1))) void*)g,
        (__attribute__((address_space(3))) void*)l, 16, 0, 0);
}

// ---------------------------------------------------------------------------
// Precision splits (unchanged, verified): G0/G1 weights and x need 3 bf16
// planes; w2 needs 2. Spike margins ~1e-7 make all kept passes required.
DEVFN void split3_chunk(const float* src, bf16* p0, bf16* p1, bf16* p2, int i) {
    float4 v = *(const float4*)(src + i);
    float vv[4] = {v.x, v.y, v.z, v.w};
    bf16x4 a, b, c;
#pragma unroll
    for (int k = 0; k < 4; ++k) {
        bf16 h0 = (bf16)vv[k];
        float r1 = vv[k] - (float)h0;      // exact
        bf16 h1 = (bf16)r1;
        float r2 = r1 - (float)h1;         // exact
        a[k] = h0; b[k] = h1; c[k] = (bf16)r2;
    }
    *(bf16x4*)(p0 + i) = a;
    *(bf16x4*)(p1 + i) = b;
    *(bf16x4*)(p2 + i) = c;
}

DEVFN void split2_chunk(const float* src, bf16* p0, bf16* p1, int i) {
    float4 v = *(const float4*)(src + i);
    float vv[4] = {v.x, v.y, v.z, v.w};
    bf16x4 a, b;
#pragma unroll
    for (int k = 0; k < 4; ++k) {
        bf16 h0 = (bf16)vv[k];
        a[k] = h0; b[k] = (bf16)(vv[k] - (float)h0);
    }
    *(bf16x4*)(p0 + i) = a;
    *(bf16x4*)(p1 + i) = b;
}

static constexpr int SB_W0 = 2048;
static constexpr int SB_W1 = 4096;
static constexpr int SB_W2 = 2048;
static constexpr int SB_X  = 6400;

__global__ void split_all(const float* __restrict__ w0, bf16* w0p0, bf16* w0p1, bf16* w0p2,
                          const float* __restrict__ w1, bf16* w1p0, bf16* w1p1, bf16* w1p2,
                          const float* __restrict__ w2, bf16* w2p0, bf16* w2p1,
                          const float* __restrict__ x,  bf16* xp0,  bf16* xp1,  bf16* xp2) {
    int b = blockIdx.x;
    if (b < SB_W0) {
        split3_chunk(w0, w0p0, w0p1, w0p2, b * 1024 + threadIdx.x * 4);
    } else if (b < SB_W0 + SB_W1) {
        split3_chunk(w1, w1p0, w1p1, w1p2, (b - SB_W0) * 1024 + threadIdx.x * 4);
    } else if (b < SB_W0 + SB_W1 + SB_W2) {
        split2_chunk(w2, w2p0, w2p1, (b - SB_W0 - SB_W1) * 1024 + threadIdx.x * 4);
    } else {
        split3_chunk(x, xp0, xp1, xp2, (b - SB_W0 - SB_W1 - SB_W2) * 1024 + threadIdx.x * 4);
    }
}

// ---------------------------------------------------------------------------
// R5: same verified schedule as R4 (16x16x32 MFMA, single __syncthreads per
// K-tile, 1-body prefetch flight, BK=64 for MODE1/2, BK=32 for MODE0, no
// setprio). Two changes, both targeting the ~1500 cyc/body non-MFMA gap:
//  (1) staging address math hoisted out of the K-loop: per-thread global
//      offsets (row*K + swizzled chunk) precomputed once; per body only +k0.
//      (VALUBusy 18% ~= 950 cyc/body of per-body address recompute.)
//  (2) critical-path reorder: the first frag-pair (a,b0) is read BEFORE the
//      stage burst so the first mfma16 unblocks ~200cyc earlier; the 9-10
//      stage issues are spread between MFMA clusters (issue-spreading like
//      m201's phases, without the extra barriers).

struct TileCtx { int t, lane, wm, wn, bm, bn, fr, fkS, fk64a, fk64b, cr, cc; };

DEVFN TileCtx make_ctx512() {
    TileCtx x;
    x.t = threadIdx.x; x.lane = x.t & 63;
    int wv = x.t >> 6;                       // 0..7
    x.wm = (wv >> 1) * 64;                   // 0,64,128,192 within BM=256
    x.wn = (wv & 1) * 64;                    // 0,64       within BN=128
    x.bm = blockIdx.x * 256; x.bn = blockIdx.y * 128;
    x.fr  = x.lane & 15;
    int g = x.lane >> 4;                     // k-chunk group
    x.fkS   = (g ^ ((x.lane >> 1) & 3)) * 16;        // BK=32 swizzled chunk, bytes
    x.fk64a = ((0 * 4 + g) ^ (x.lane & 7)) * 16;     // BK=64, k-half 0
    x.fk64b = ((1 * 4 + g) ^ (x.lane & 7)) * 16;     // BK=64, k-half 1
    x.cr = (x.lane >> 4) * 4; x.cc = x.lane & 15;
    return x;
}

// swizzled LDS fragment read; row stride = 2*BK bytes
template <int BK>
DEVFN void frag4(bf16x8* f, const bf16* s, int wrow, int fr, int fkS) {
#pragma unroll
    for (int i = 0; i < 4; ++i)
        f[i] = *(const bf16x8*)((const char*)s + (wrow + i * 16 + fr) * (2 * BK) + fkS);
}

DEVFN void mfma16(f32x4 (&acc)[4][4], const bf16x8* a, const bf16x8* b) {
#pragma unroll
    for (int i = 0; i < 4; ++i)
#pragma unroll
        for (int j = 0; j < 4; ++j)
            acc[i][j] = __builtin_amdgcn_mfma_f32_16x16x32_bf16(a[i], b[j], acc[i][j], 0, 0, 0);
}

// fp64 merge: accM + accS + bias summed in double, single round to f32.
DEVFN void epilogue(const f32x4 (&accM)[4][4], const f32x4 (&accS)[4][4],
                    const float* bias, float* C, int N, const TileCtx& x) {
#pragma unroll
    for (int j = 0; j < 4; ++j) {
        int col   = x.bn + x.wn + j * 16 + x.cc;
        double bv = (double)bias[col];
#pragma unroll
        for (int i = 0; i < 4; ++i) {
            int row0 = x.bm + x.wm + i * 16 + x.cr;
#pragma unroll
            for (int r = 0; r < 4; ++r) {
                double v = (double)accM[i][j][r] + (double)accS[i][j][r] + bv;
                C[(size_t)(row0 + r) * N + col] = (float)v;
            }
        }
    }
}

// MODE 0: L0 (3 A planes, 3 B planes, 6 passes, BK=32)
// MODE 1: L1 (1 A plane,  3 B planes, 3 passes, BK=64)
// MODE 2: L2 (1 A plane,  2 B planes, 2 passes, BK=64)
template <int MODE>
__global__ __launch_bounds__(512, 2)
void gemm_ph(const bf16* __restrict__ A0, const bf16* __restrict__ A1,
             const bf16* __restrict__ A2, const bf16* __restrict__ B0,
             const bf16* __restrict__ B1, const bf16* __restrict__ B2,
             const float* __restrict__ bias, float* __restrict__ C,
             int M, int N, int K) {
    constexpr int BK  = (MODE == 0) ? 32 : 64;
    constexpr int CPR = BK / 8;              // 16B chunks per row (4 or 8)
    constexpr int AIT = CPR / 2;             // llds16 per 256-row plane (2 / 4)
    constexpr int BIT = CPR / 4;             // llds16 per 128-row plane (1 / 2)
    constexpr int NA  = (MODE == 0) ? 3 : 1;
    constexpr int NB  = (MODE == 2) ? 2 : 3;
    constexpr int APL = 256 * BK;            // A plane elems
    constexpr int BPL = 128 * BK;            // B plane elems
    constexpr int BUF = NA * APL + NB * BPL;
    __shared__ __align__(1024) bf16 lds[2 * BUF];   // MODE0:144K 1:160K 2:128K

    TileCtx x = make_ctx512();
    f32x4 accM[4][4] = {}, accS[4][4] = {};

    auto pA = [&](int p, int i) { return lds + p * BUF + i * APL; };
    auto pB = [&](int p, int i) { return lds + p * BUF + NA * APL + i * BPL; };

    // (1) staging addresses hoisted: per-thread global offsets, LDS dest slots
    size_t offA[AIT], offB[BIT];
#pragma unroll
    for (int r = 0; r < AIT; ++r) {
        int c = x.t + r * 512, row = c / CPR, slot = c % CPR;
        int src = (BK == 32) ? (slot ^ ((row >> 1) & 3)) : (slot ^ (row & 7));
        offA[r] = (size_t)(x.bm + row) * K + src * 8;
    }
#pragma unroll
    for (int r = 0; r < BIT; ++r) {
        int c = x.t + r * 512, row = c / CPR, slot = c % CPR;
        int src = (BK == 32) ? (slot ^ ((row >> 1) & 3)) : (slot ^ (row & 7));
        offB[r] = (size_t)(x.bn + row) * K + src * 8;
    }
    auto stA = [&](const bf16* g, bf16* s, int k0) {
#pragma unroll
        for (int r = 0; r < AIT; ++r)
            llds16(g + offA[r] + k0, (char*)s + ((x.t + r * 512) >> 6) * 1024);
    };
    auto stB = [&](const bf16* g, bf16* s, int k0) {
#pragma unroll
        for (int r = 0; r < BIT; ++r)
            llds16(g + offB[r] + k0, (char*)s + ((x.t + r * 512) >> 6) * 1024);
    };

    // prologue: tile 0 into buf 0; the one full-latency drain of the kernel
    stA(A0, pA(0, 0), 0);
    if constexpr (MODE == 0) { stA(A1, pA(0, 1), 0); stA(A2, pA(0, 2), 0); }
    stB(B0, pB(0, 0), 0);
    stB(B1, pB(0, 1), 0);
    if constexpr (NB == 3) stB(B2, pB(0, 2), 0);
    __syncthreads();

    const int NT = K / BK;
    int p = 0;
    for (int tt = 0; tt < NT; ++tt, p ^= 1) {
        const int  q  = p ^ 1;
        const int  kn = (tt + 1) * BK;
        const bool pf = (tt + 1 < NT);
        bf16x8 a[4], b0f[4], b1f[4], b2f[4];

        if constexpr (MODE == 0) {
            // (2) critical frags first, stages spread between MFMA clusters
            frag4<32>(a,   pA(p, 0), x.wm, x.fr, x.fkS);
            frag4<32>(b0f, pB(p, 0), x.wn, x.fr, x.fkS);
            if (pf) stA(A0, pA(q, 0), kn);
            mfma16(accM, a, b0f);
            if (pf) { stA(A1, pA(q, 1), kn); stA(A2, pA(q, 2), kn); }
            frag4<32>(b1f, pB(p, 1), x.wn, x.fr, x.fkS);
            mfma16(accS, a, b1f);
            if (pf) { stB(B0, pB(q, 0), kn); stB(B1, pB(q, 1), kn); stB(B2, pB(q, 2), kn); }
            frag4<32>(b2f, pB(p, 2), x.wn, x.fr, x.fkS);
            mfma16(accS, a, b2f);
            frag4<32>(a, pA(p, 1), x.wm, x.fr, x.fkS);   // a1
            mfma16(accS, a, b0f);
            mfma16(accS, a, b1f);
            frag4<32>(a, pA(p, 2), x.wm, x.fr, x.fkS);   // a2
            mfma16(accS, a, b0f);
        } else if constexpr (MODE == 1) {
            // k-half 0 (carries the staging)
            frag4<64>(a,   pA(p, 0), x.wm, x.fr, x.fk64a);
            frag4<64>(b0f, pB(p, 0), x.wn, x.fr, x.fk64a);
            if (pf) stA(A0, pA(q, 0), kn);
            mfma16(accM, a, b0f);
            if (pf) { stB(B0, pB(q, 0), kn); stB(B1, pB(q, 1), kn); }
            frag4<64>(b1f, pB(p, 1), x.wn, x.fr, x.fk64a);
            mfma16(accS, a, b1f);
            if (pf) stB(B2, pB(q, 2), kn);
            frag4<64>(b2f, pB(p, 2), x.wn, x.fr, x.fk64a);
            mfma16(accS, a, b2f);
            // k-half 1
            frag4<64>(a,   pA(p, 0), x.wm, x.fr, x.fk64b);
            frag4<64>(b0f, pB(p, 0), x.wn, x.fr, x.fk64b);
            mfma16(accM, a, b0f);
            frag4<64>(b1f, pB(p, 1), x.wn, x.fr, x.fk64b);
            mfma16(accS, a, b1f);
            frag4<64>(b2f, pB(p, 2), x.wn, x.fr, x.fk64b);
            mfma16(accS, a, b2f);
        } else {
            frag4<64>(a,   pA(p, 0), x.wm, x.fr, x.fk64a);
            frag4<64>(b0f, pB(p, 0), x.wn, x.fr, x.fk64a);
            if (pf) stA(A0, pA(q, 0), kn);
            mfma16(accM, a, b0f);
            if (pf) { stB(B0, pB(q, 0), kn); stB(B1, pB(q, 1), kn); }
            frag4<64>(b1f, pB(p, 1), x.wn, x.fr, x.fk64a);
            mfma16(accS, a, b1f);
            frag4<64>(a,   pA(p, 0), x.wm, x.fr, x.fk64b);
            frag4<64>(b0f, pB(p, 0), x.wn, x.fr, x.fk64b);
            mfma16(accM, a, b0f);
            frag4<64>(b1f, pB(p, 1), x.wn, x.fr, x.fk64b);
            mfma16(accS, a, b1f);
        }
        // single per-tile barrier: gates buf(q) visibility for next tile and
        // protects buf(p) against next tile's stages (readers are done here).
        __syncthreads();
    }
    epilogue(accM, accS, bias, C, N, x);
}

// ---------------------------------------------------------------------------
// LIF scans — fp64 recurrence (verified: kills the f32 drift flips).
template <int F>
__global__ void lif_hidden(const float* __restrict__ cur, bf16* __restrict__ spk) {
    const int tid = blockIdx.x * 256 + threadIdx.x;  // b*F + f
    double m = 0.0;
    size_t off = tid;
#pragma unroll
    for (int t = 0; t < T_STEPS; ++t) {
        m = 0.9 * m + (double)cur[off];
        bool s = (m - 1.0) > 0.0;
        spk[off] = (bf16)(s ? 1.0f : 0.0f);
        if (s) m -= 1.0;
        off += (size_t)BATCH * F;
    }
}

__global__ void lif_out(const float* __restrict__ cur, float* __restrict__ out) {
    const int tid = blockIdx.x * 256 + threadIdx.x;  // b*1024 + f
    double m = 0.0;
    size_t off = tid;
#pragma unroll
    for (int t = 0; t < T_STEPS; ++t) {
        m = 0.9 * m + (double)cur[off];
        bool s = (m - 1.0) > 0.0;
        out[off] = s ? 1.0f : 0.0f;
        if (s) m -= 1.0;
        off += (size_t)BATCH * 1024;
    }
    out[(size_t)T_STEPS * BATCH * 1024 + tid] = (float)m;  // final membrane (output 1)
}

// ---------------------------------------------------------------------------
extern "C" void kernel_launch(void* const* d_in, const int* in_sizes, int n_in,
                              void* d_out, int out_size, void* d_ws, size_t ws_size,
                              hipStream_t stream) {
    const float* xin = (const float*)d_in[0];
    const float* w0  = (const float*)d_in[1];
    const float* b0  = (const float*)d_in[2];
    const float* w1  = (const float*)d_in[3];
    const float* b1  = (const float*)d_in[4];
    const float* w2  = (const float*)d_in[5];
    const float* b2  = (const float*)d_in[6];
    float* out = (float*)d_out;

    constexpr size_t NW0 = 2048 * 1024;
    constexpr size_t NW1 = 2048 * 2048;
    constexpr size_t NW2 = 1024 * 2048;
    constexpr size_t NX  = (size_t)MROWS * 1024;  // 6,553,600
    constexpr size_t NH  = (size_t)MROWS * 2048;  // 13,107,200

    char* ws = (char*)d_ws;
    size_t off = 0;
    auto carve = [&](size_t bytes) { char* p = ws + off; off += bytes; return p; };

    // long-lived planes
    bf16* w1p0 = (bf16*)carve(NW1 * 2);
    bf16* w1p1 = (bf16*)carve(NW1 * 2);
    bf16* w1p2 = (bf16*)carve(NW1 * 2);
    bf16* w2p0 = (bf16*)carve(NW2 * 2);
    bf16* w2p1 = (bf16*)carve(NW2 * 2);
    // pool: w0 planes + x planes live only until G0; s0/s1 overlay afterwards
    char* pool = carve(2 * NH * 2);          // 52,428,800 B
    bf16* w0p0 = (bf16*)pool;
    bf16* w0p1 = w0p0 + NW0;
    bf16* w0p2 = w0p1 + NW0;
    bf16* xp0  = w0p2 + NW0;
    bf16* xp1  = xp0 + NX;
    bf16* xp2  = xp1 + NX;                   // ends at pool + 51,904,512
    bf16* s0   = (bf16*)pool;                // written after G0 consumed w0/x
    bf16* s1   = s0 + NH;                    // written after G1 consumed s0
    float* cur = (float*)carve(NH * 4);
    if (ws_size < off) return;               // 138,412,032 B total

    // 1) fused precision splits (one launch)
    split_all<<<SB_W0 + SB_W1 + SB_W2 + SB_X, 256, 0, stream>>>(
        w0, w0p0, w0p1, w0p2, w1, w1p0, w1p1, w1p2,
        w2, w2p0, w2p1, xin, xp0, xp1, xp2);

    // 2) layer 0: cur0 = x @ W0^T + b0 (M=6400,N=2048,K=1024; 6-pass dual-acc)
    gemm_ph<0><<<dim3(25, 16), 512, 0, stream>>>(xp0, xp1, xp2, w0p0, w0p1, w0p2,
                                                 b0, cur, MROWS, 2048, 1024);
    lif_hidden<2048><<<(BATCH * 2048) / 256, 256, 0, stream>>>(cur, s0);

    // 3) layer 1: cur1 = s0 @ W1^T + b1 (K=2048; 3-pass dual-acc, BK=64)
    gemm_ph<1><<<dim3(25, 16), 512, 0, stream>>>(s0, nullptr, nullptr, w1p0, w1p1, w1p2,
                                                 b1, cur, MROWS, 2048, 2048);
    lif_hidden<2048><<<(BATCH * 2048) / 256, 256, 0, stream>>>(cur, s1);

    // 4) layer 2: cur2 = s1 @ W2^T + b2 (N=1024; 2-pass dual-acc, BK=64)
    gemm_ph<2><<<dim3(25, 8), 512, 0, stream>>>(s1, nullptr, nullptr, w2p0, w2p1, nullptr,
                                                b2, cur, MROWS, 1024, 2048);
    lif_out<<<(BATCH * 1024) / 256, 256, 0, stream>>>(cur, out);
}

// Round 6
// 460.526 us; speedup vs baseline: 1.1706x; 1.0101x over previous
//
#include <hip/hip_runtime.h>
#include <hip/hip_bf16.h>

typedef __bf16 bf16;
typedef __bf16 bf16x4 __attribute__((ext_vector_type(4)));
typedef __bf16 bf16x8 __attribute__((ext_vector_type(8)));
typedef float  f32x4  __attribute__((ext_vector_type(4)));

#define DEVFN static __device__ __forceinline__

static constexpr int T_STEPS = 25;
static constexpr int BATCH   = 256;
static constexpr int MROWS   = T_STEPS * BATCH;  // 6400

// async global->LDS, 16B/lane; LDS base must be wave-uniform (HW adds lane*16).
DEVFN void llds16(const void* g, void* l) {
    __builtin_amdgcn_global_load_lds(
        (const __attribute__((address_space(1))) void*)g,
        (__attribute__((address_space(3))) void*)l, 16, 0, 0);
}

// ---------------------------------------------------------------------------
// Precision splits (unchanged, verified): G0/G1 weights and x need 3 bf16
// planes; w2 needs 2. Spike margins ~1e-7 make all kept passes required.
DEVFN void split3_chunk(const float* src, bf16* p0, bf16* p1, bf16* p2, int i) {
    float4 v = *(const float4*)(src + i);
    float vv[4] = {v.x, v.y, v.z, v.w};
    bf16x4 a, b, c;
#pragma unroll
    for (int k = 0; k < 4; ++k) {
        bf16 h0 = (bf16)vv[k];
        float r1 = vv[k] - (float)h0;      // exact
        bf16 h1 = (bf16)r1;
        float r2 = r1 - (float)h1;         // exact
        a[k] = h0; b[k] = h1; c[k] = (bf16)r2;
    }
    *(bf16x4*)(p0 + i) = a;
    *(bf16x4*)(p1 + i) = b;
    *(bf16x4*)(p2 + i) = c;
}

DEVFN void split2_chunk(const float* src, bf16* p0, bf16* p1, int i) {
    float4 v = *(const float4*)(src + i);
    float vv[4] = {v.x, v.y, v.z, v.w};
    bf16x4 a, b;
#pragma unroll
    for (int k = 0; k < 4; ++k) {
        bf16 h0 = (bf16)vv[k];
        a[k] = h0; b[k] = (bf16)(vv[k] - (float)h0);
    }
    *(bf16x4*)(p0 + i) = a;
    *(bf16x4*)(p1 + i) = b;
}

static constexpr int SB_W0 = 2048;
static constexpr int SB_W1 = 4096;
static constexpr int SB_W2 = 2048;
static constexpr int SB_X  = 6400;

__global__ void split_all(const float* __restrict__ w0, bf16* w0p0, bf16* w0p1, bf16* w0p2,
                          const float* __restrict__ w1, bf16* w1p0, bf16* w1p1, bf16* w1p2,
                          const float* __restrict__ w2, bf16* w2p0, bf16* w2p1,
                          const float* __restrict__ x,  bf16* xp0,  bf16* xp1,  bf16* xp2) {
    int b = blockIdx.x;
    if (b < SB_W0) {
        split3_chunk(w0, w0p0, w0p1, w0p2, b * 1024 + threadIdx.x * 4);
    } else if (b < SB_W0 + SB_W1) {
        split3_chunk(w1, w1p0, w1p1, w1p2, (b - SB_W0) * 1024 + threadIdx.x * 4);
    } else if (b < SB_W0 + SB_W1 + SB_W2) {
        split2_chunk(w2, w2p0, w2p1, (b - SB_W0 - SB_W1) * 1024 + threadIdx.x * 4);
    } else {
        split3_chunk(x, xp0, xp1, xp2, (b - SB_W0 - SB_W1 - SB_W2) * 1024 + threadIdx.x * 4);
    }
}

// ---------------------------------------------------------------------------
// R6: wave-pair phase stagger. Residency is 2 waves/SIMD (1 block/CU, 236
// regs), SIMD s hosts waves s and s+4 (wv%4 round-robin). R5 showed both
// partner waves run the identical body in lockstep -> they hit every
// frag-read lgkm-wait simultaneously and the SIMD idles (~2000 cyc/body gap,
// unexplained by VALU/conflicts/HBM). Fix: waves 4-7 execute the SAME passes
// in a rotated order (start half-way through the sequence), so one wave's
// MFMA cluster overlaps its partner's frag-read wait. Pass order within a
// body is semantically free (all passes accumulate; rounding perturbation
// ~2^-30 rel << 1e-7 spike margins). With genuine phase diversity, setprio(1)
// around MFMA clusters is re-enabled (m218b/m191: pays only in this regime;
// m190's null was the lockstep case this round eliminates).

struct TileCtx { int t, lane, wm, wn, bm, bn, fr, fkS, fk64a, fk64b, cr, cc, sk; };

DEVFN TileCtx make_ctx512() {
    TileCtx x;
    x.t = threadIdx.x; x.lane = x.t & 63;
    int wv = x.t >> 6;                       // 0..7
    x.wm = (wv >> 1) * 64;                   // 0,64,128,192 within BM=256
    x.wn = (wv & 1) * 64;                    // 0,64       within BN=128
    x.bm = blockIdx.x * 256; x.bn = blockIdx.y * 128;
    x.sk = (wv >> 2) & 1;                    // stagger key: SIMD partner parity
    x.fr  = x.lane & 15;
    int g = x.lane >> 4;                     // k-chunk group
    x.fkS   = (g ^ ((x.lane >> 1) & 3)) * 16;        // BK=32 swizzled chunk, bytes
    x.fk64a = ((0 * 4 + g) ^ (x.lane & 7)) * 16;     // BK=64, k-half 0
    x.fk64b = ((1 * 4 + g) ^ (x.lane & 7)) * 16;     // BK=64, k-half 1
    x.cr = (x.lane >> 4) * 4; x.cc = x.lane & 15;
    return x;
}

// swizzled LDS fragment read; row stride = 2*BK bytes
template <int BK>
DEVFN void frag4(bf16x8* f, const bf16* s, int wrow, int fr, int fkS) {
#pragma unroll
    for (int i = 0; i < 4; ++i)
        f[i] = *(const bf16x8*)((const char*)s + (wrow + i * 16 + fr) * (2 * BK) + fkS);
}

DEVFN void mfma16(f32x4 (&acc)[4][4], const bf16x8* a, const bf16x8* b) {
    __builtin_amdgcn_s_setprio(1);
#pragma unroll
    for (int i = 0; i < 4; ++i)
#pragma unroll
        for (int j = 0; j < 4; ++j)
            acc[i][j] = __builtin_amdgcn_mfma_f32_16x16x32_bf16(a[i], b[j], acc[i][j], 0, 0, 0);
    __builtin_amdgcn_s_setprio(0);
}

// fp64 merge: accM + accS + bias summed in double, single round to f32.
DEVFN void epilogue(const f32x4 (&accM)[4][4], const f32x4 (&accS)[4][4],
                    const float* bias, float* C, int N, const TileCtx& x) {
#pragma unroll
    for (int j = 0; j < 4; ++j) {
        int col   = x.bn + x.wn + j * 16 + x.cc;
        double bv = (double)bias[col];
#pragma unroll
        for (int i = 0; i < 4; ++i) {
            int row0 = x.bm + x.wm + i * 16 + x.cr;
#pragma unroll
            for (int r = 0; r < 4; ++r) {
                double v = (double)accM[i][j][r] + (double)accS[i][j][r] + bv;
                C[(size_t)(row0 + r) * N + col] = (float)v;
            }
        }
    }
}

// MODE 0: L0 (3 A planes, 3 B planes, 6 passes, BK=32)
// MODE 1: L1 (1 A plane,  3 B planes, 3 passes, BK=64)
// MODE 2: L2 (1 A plane,  2 B planes, 2 passes, BK=64)
template <int MODE>
__global__ __launch_bounds__(512, 2)
void gemm_ph(const bf16* __restrict__ A0, const bf16* __restrict__ A1,
             const bf16* __restrict__ A2, const bf16* __restrict__ B0,
             const bf16* __restrict__ B1, const bf16* __restrict__ B2,
             const float* __restrict__ bias, float* __restrict__ C,
             int M, int N, int K) {
    constexpr int BK  = (MODE == 0) ? 32 : 64;
    constexpr int CPR = BK / 8;              // 16B chunks per row (4 or 8)
    constexpr int AIT = CPR / 2;             // llds16 per 256-row plane (2 / 4)
    constexpr int BIT = CPR / 4;             // llds16 per 128-row plane (1 / 2)
    constexpr int NA  = (MODE == 0) ? 3 : 1;
    constexpr int NB  = (MODE == 2) ? 2 : 3;
    constexpr int APL = 256 * BK;            // A plane elems
    constexpr int BPL = 128 * BK;            // B plane elems
    constexpr int BUF = NA * APL + NB * BPL;
    __shared__ __align__(1024) bf16 lds[2 * BUF];   // MODE0:144K 1:160K 2:128K

    TileCtx x = make_ctx512();
    f32x4 accM[4][4] = {}, accS[4][4] = {};

    auto pA = [&](int p, int i) { return lds + p * BUF + i * APL; };
    auto pB = [&](int p, int i) { return lds + p * BUF + NA * APL + i * BPL; };

    // staging addresses hoisted: per-thread global offsets, LDS dest slots
    size_t offA[AIT], offB[BIT];
#pragma unroll
    for (int r = 0; r < AIT; ++r) {
        int c = x.t + r * 512, row = c / CPR, slot = c % CPR;
        int src = (BK == 32) ? (slot ^ ((row >> 1) & 3)) : (slot ^ (row & 7));
        offA[r] = (size_t)(x.bm + row) * K + src * 8;
    }
#pragma unroll
    for (int r = 0; r < BIT; ++r) {
        int c = x.t + r * 512, row = c / CPR, slot = c % CPR;
        int src = (BK == 32) ? (slot ^ ((row >> 1) & 3)) : (slot ^ (row & 7));
        offB[r] = (size_t)(x.bn + row) * K + src * 8;
    }
    auto stA = [&](const bf16* g, bf16* s, int k0) {
#pragma unroll
        for (int r = 0; r < AIT; ++r)
            llds16(g + offA[r] + k0, (char*)s + ((x.t + r * 512) >> 6) * 1024);
    };
    auto stB = [&](const bf16* g, bf16* s, int k0) {
#pragma unroll
        for (int r = 0; r < BIT; ++r)
            llds16(g + offB[r] + k0, (char*)s + ((x.t + r * 512) >> 6) * 1024);
    };

    // prologue: tile 0 into buf 0; the one full-latency drain of the kernel
    stA(A0, pA(0, 0), 0);
    if constexpr (MODE == 0) { stA(A1, pA(0, 1), 0); stA(A2, pA(0, 2), 0); }
    stB(B0, pB(0, 0), 0);
    stB(B1, pB(0, 1), 0);
    if constexpr (NB == 3) stB(B2, pB(0, 2), 0);
    __syncthreads();

    const int NT = K / BK;
    int p = 0;
    for (int tt = 0; tt < NT; ++tt, p ^= 1) {
        const int  q  = p ^ 1;
        const int  kn = (tt + 1) * BK;
        const bool pf = (tt + 1 < NT);
        bf16x8 a[4], b0f[4], b1f[4], b2f[4];

        if constexpr (MODE == 0) {
            if (x.sk == 0) {
                // order A: P0 P1 P2 P3 P4 P5
                frag4<32>(a,   pA(p, 0), x.wm, x.fr, x.fkS);
                frag4<32>(b0f, pB(p, 0), x.wn, x.fr, x.fkS);
                if (pf) stA(A0, pA(q, 0), kn);
                mfma16(accM, a, b0f);                        // P0 a0b0
                if (pf) { stA(A1, pA(q, 1), kn); stA(A2, pA(q, 2), kn); }
                frag4<32>(b1f, pB(p, 1), x.wn, x.fr, x.fkS);
                mfma16(accS, a, b1f);                        // P1 a0b1
                if (pf) { stB(B0, pB(q, 0), kn); stB(B1, pB(q, 1), kn); stB(B2, pB(q, 2), kn); }
                frag4<32>(b2f, pB(p, 2), x.wn, x.fr, x.fkS);
                mfma16(accS, a, b2f);                        // P2 a0b2
                frag4<32>(a, pA(p, 1), x.wm, x.fr, x.fkS);
                mfma16(accS, a, b0f);                        // P3 a1b0
                mfma16(accS, a, b1f);                        // P4 a1b1
                frag4<32>(a, pA(p, 2), x.wm, x.fr, x.fkS);
                mfma16(accS, a, b0f);                        // P5 a2b0
            } else {
                // order B: P3 P4 P5 P0 P1 P2 (rotated half-way)
                frag4<32>(a,   pA(p, 1), x.wm, x.fr, x.fkS); // a1
                frag4<32>(b0f, pB(p, 0), x.wn, x.fr, x.fkS);
                if (pf) stA(A0, pA(q, 0), kn);
                mfma16(accS, a, b0f);                        // P3 a1b0
                if (pf) { stA(A1, pA(q, 1), kn); stA(A2, pA(q, 2), kn); }
                frag4<32>(b1f, pB(p, 1), x.wn, x.fr, x.fkS);
                mfma16(accS, a, b1f);                        // P4 a1b1
                if (pf) { stB(B0, pB(q, 0), kn); stB(B1, pB(q, 1), kn); stB(B2, pB(q, 2), kn); }
                frag4<32>(a, pA(p, 2), x.wm, x.fr, x.fkS);
                mfma16(accS, a, b0f);                        // P5 a2b0
                frag4<32>(a, pA(p, 0), x.wm, x.fr, x.fkS);   // a0
                mfma16(accM, a, b0f);                        // P0 a0b0
                frag4<32>(b2f, pB(p, 2), x.wn, x.fr, x.fkS);
                mfma16(accS, a, b1f);                        // P1 a0b1
                mfma16(accS, a, b2f);                        // P2 a0b2
            }
        } else if constexpr (MODE == 1) {
            const int fkFirst  = x.sk ? x.fk64b : x.fk64a;
            const int fkSecond = x.sk ? x.fk64a : x.fk64b;
            // first k-half (carries the staging)
            frag4<64>(a,   pA(p, 0), x.wm, x.fr, fkFirst);
            frag4<64>(b0f, pB(p, 0), x.wn, x.fr, fkFirst);
            if (pf) stA(A0, pA(q, 0), kn);
            mfma16(accM, a, b0f);
            if (pf) { stB(B0, pB(q, 0), kn); stB(B1, pB(q, 1), kn); }
            frag4<64>(b1f, pB(p, 1), x.wn, x.fr, fkFirst);
            mfma16(accS, a, b1f);
            if (pf) stB(B2, pB(q, 2), kn);
            frag4<64>(b2f, pB(p, 2), x.wn, x.fr, fkFirst);
            mfma16(accS, a, b2f);
            // second k-half
            frag4<64>(a,   pA(p, 0), x.wm, x.fr, fkSecond);
            frag4<64>(b0f, pB(p, 0), x.wn, x.fr, fkSecond);
            mfma16(accM, a, b0f);
            frag4<64>(b1f, pB(p, 1), x.wn, x.fr, fkSecond);
            mfma16(accS, a, b1f);
            frag4<64>(b2f, pB(p, 2), x.wn, x.fr, fkSecond);
            mfma16(accS, a, b2f);
        } else {
            const int fkFirst  = x.sk ? x.fk64b : x.fk64a;
            const int fkSecond = x.sk ? x.fk64a : x.fk64b;
            frag4<64>(a,   pA(p, 0), x.wm, x.fr, fkFirst);
            frag4<64>(b0f, pB(p, 0), x.wn, x.fr, fkFirst);
            if (pf) stA(A0, pA(q, 0), kn);
            mfma16(accM, a, b0f);
            if (pf) { stB(B0, pB(q, 0), kn); stB(B1, pB(q, 1), kn); }
            frag4<64>(b1f, pB(p, 1), x.wn, x.fr, fkFirst);
            mfma16(accS, a, b1f);
            frag4<64>(a,   pA(p, 0), x.wm, x.fr, fkSecond);
            frag4<64>(b0f, pB(p, 0), x.wn, x.fr, fkSecond);
            mfma16(accM, a, b0f);
            frag4<64>(b1f, pB(p, 1), x.wn, x.fr, fkSecond);
            mfma16(accS, a, b1f);
        }
        // single per-tile barrier: gates buf(q) visibility for next tile and
        // protects buf(p) against next tile's stages (readers are done here).
        __syncthreads();
    }
    epilogue(accM, accS, bias, C, N, x);
}

// ---------------------------------------------------------------------------
// LIF scans — fp64 recurrence (verified: kills the f32 drift flips).
template <int F>
__global__ void lif_hidden(const float* __restrict__ cur, bf16* __restrict__ spk) {
    const int tid = blockIdx.x * 256 + threadIdx.x;  // b*F + f
    double m = 0.0;
    size_t off = tid;
#pragma unroll
    for (int t = 0; t < T_STEPS; ++t) {
        m = 0.9 * m + (double)cur[off];
        bool s = (m - 1.0) > 0.0;
        spk[off] = (bf16)(s ? 1.0f : 0.0f);
        if (s) m -= 1.0;
        off += (size_t)BATCH * F;
    }
}

__global__ void lif_out(const float* __restrict__ cur, float* __restrict__ out) {
    const int tid = blockIdx.x * 256 + threadIdx.x;  // b*1024 + f
    double m = 0.0;
    size_t off = tid;
#pragma unroll
    for (int t = 0; t < T_STEPS; ++t) {
        m = 0.9 * m + (double)cur[off];
        bool s = (m - 1.0) > 0.0;
        out[off] = s ? 1.0f : 0.0f;
        if (s) m -= 1.0;
        off += (size_t)BATCH * 1024;
    }
    out[(size_t)T_STEPS * BATCH * 1024 + tid] = (float)m;  // final membrane (output 1)
}

// ---------------------------------------------------------------------------
extern "C" void kernel_launch(void* const* d_in, const int* in_sizes, int n_in,
                              void* d_out, int out_size, void* d_ws, size_t ws_size,
                              hipStream_t stream) {
    const float* xin = (const float*)d_in[0];
    const float* w0  = (const float*)d_in[1];
    const float* b0  = (const float*)d_in[2];
    const float* w1  = (const float*)d_in[3];
    const float* b1  = (const float*)d_in[4];
    const float* w2  = (const float*)d_in[5];
    const float* b2  = (const float*)d_in[6];
    float* out = (float*)d_out;

    constexpr size_t NW0 = 2048 * 1024;
    constexpr size_t NW1 = 2048 * 2048;
    constexpr size_t NW2 = 1024 * 2048;
    constexpr size_t NX  = (size_t)MROWS * 1024;  // 6,553,600
    constexpr size_t NH  = (size_t)MROWS * 2048;  // 13,107,200

    char* ws = (char*)d_ws;
    size_t off = 0;
    auto carve = [&](size_t bytes) { char* p = ws + off; off += bytes; return p; };

    // long-lived planes
    bf16* w1p0 = (bf16*)carve(NW1 * 2);
    bf16* w1p1 = (bf16*)carve(NW1 * 2);
    bf16* w1p2 = (bf16*)carve(NW1 * 2);
    bf16* w2p0 = (bf16*)carve(NW2 * 2);
    bf16* w2p1 = (bf16*)carve(NW2 * 2);
    // pool: w0 planes + x planes live only until G0; s0/s1 overlay afterwards
    char* pool = carve(2 * NH * 2);          // 52,428,800 B
    bf16* w0p0 = (bf16*)pool;
    bf16* w0p1 = w0p0 + NW0;
    bf16* w0p2 = w0p1 + NW0;
    bf16* xp0  = w0p2 + NW0;
    bf16* xp1  = xp0 + NX;
    bf16* xp2  = xp1 + NX;                   // ends at pool + 51,904,512
    bf16* s0   = (bf16*)pool;                // written after G0 consumed w0/x
    bf16* s1   = s0 + NH;                    // written after G1 consumed s0
    float* cur = (float*)carve(NH * 4);
    if (ws_size < off) return;               // 138,412,032 B total

    // 1) fused precision splits (one launch)
    split_all<<<SB_W0 + SB_W1 + SB_W2 + SB_X, 256, 0, stream>>>(
        w0, w0p0, w0p1, w0p2, w1, w1p0, w1p1, w1p2,
        w2, w2p0, w2p1, xin, xp0, xp1, xp2);

    // 2) layer 0: cur0 = x @ W0^T + b0 (M=6400,N=2048,K=1024; 6-pass dual-acc)
    gemm_ph<0><<<dim3(25, 16), 512, 0, stream>>>(xp0, xp1, xp2, w0p0, w0p1, w0p2,
                                                 b0, cur, MROWS, 2048, 1024);
    lif_hidden<2048><<<(BATCH * 2048) / 256, 256, 0, stream>>>(cur, s0);

    // 3) layer 1: cur1 = s0 @ W1^T + b1 (K=2048; 3-pass dual-acc, BK=64)
    gemm_ph<1><<<dim3(25, 16), 512, 0, stream>>>(s0, nullptr, nullptr, w1p0, w1p1, w1p2,
                                                 b1, cur, MROWS, 2048, 2048);
    lif_hidden<2048><<<(BATCH * 2048) / 256, 256, 0, stream>>>(cur, s1);

    // 4) layer 2: cur2 = s1 @ W2^T + b2 (N=1024; 2-pass dual-acc, BK=64)
    gemm_ph<2><<<dim3(25, 8), 512, 0, stream>>>(s1, nullptr, nullptr, w2p0, w2p1, nullptr,
                                                b2, cur, MROWS, 1024, 2048);
    lif_out<<<(BATCH * 1024) / 256, 256, 0, stream>>>(cur, out);
}

// Round 7
// 412.412 us; speedup vs baseline: 1.3072x; 1.1167x over previous
//
#include <hip/hip_runtime.h>
#include <hip/hip_bf16.h>

typedef __bf16 bf16;
typedef __bf16 bf16x4 __attribute__((ext_vector_type(4)));
typedef __bf16 bf16x8 __attribute__((ext_vector_type(8)));
typedef float  f32x4  __attribute__((ext_vector_type(4)));
typedef signed char i8;
typedef signed char i8x4 __attribute__((ext_vector_type(4)));
typedef int    i32x4 __attribute__((ext_vector_type(4)));

#define DEVFN static __device__ __forceinline__

static constexpr int T_STEPS = 25;
static constexpr int BATCH   = 256;
static constexpr int MROWS   = T_STEPS * BATCH;  // 6400

// async global->LDS, 16B/lane; LDS base must be wave-uniform (HW adds lane*16).
DEVFN void llds16(const void* g, void* l) {
    __builtin_amdgcn_global_load_lds(
        (const __attribute__((address_space(1))) void*)g,
        (__attribute__((address_space(3))) void*)l, 16, 0, 0);
}

// ---------------------------------------------------------------------------
// Precision splits.
// L0 (x, w0): bf16 3-plane (verified). L1/L2 weights: NEW balanced base-128 i8
// digit planes: w*4096 = p0 + p1/128 + p2/128^2 + r/2^21, |w|<=1/sqrt(2048)
// -> |p0|<=91, |p1|,|p2|<=64. All steps exact in f32 (pow-2 scales). Residual
// per entry: 3 planes 2^-34 (beats verified 3xbf16 = 2^-32.5), 2 planes 2^-27
// (10x better than verified-sufficient 2xbf16 for L2). i32 accumulation is
// EXACT -> numerics strictly better than the current passing scheme.
DEVFN void split3_chunk(const float* src, bf16* p0, bf16* p1, bf16* p2, int i) {
    float4 v = *(const float4*)(src + i);
    float vv[4] = {v.x, v.y, v.z, v.w};
    bf16x4 a, b, c;
#pragma unroll
    for (int k = 0; k < 4; ++k) {
        bf16 h0 = (bf16)vv[k];
        float r1 = vv[k] - (float)h0;      // exact
        bf16 h1 = (bf16)r1;
        float r2 = r1 - (float)h1;         // exact
        a[k] = h0; b[k] = h1; c[k] = (bf16)r2;
    }
    *(bf16x4*)(p0 + i) = a;
    *(bf16x4*)(p1 + i) = b;
    *(bf16x4*)(p2 + i) = c;
}

DEVFN void spliti8_3(const float* src, i8* p0, i8* p1, i8* p2, int i) {
    float4 v = *(const float4*)(src + i);
    float vv[4] = {v.x, v.y, v.z, v.w};
    i8x4 a, b, c;
#pragma unroll
    for (int k = 0; k < 4; ++k) {
        float t  = vv[k] * 4096.0f;              // exact (pow2)
        float q0 = rintf(t);  float r = t - q0;             // exact
        float q1 = rintf(r * 128.0f); r = r * 128.0f - q1;  // exact
        float q2 = rintf(r * 128.0f);
        a[k] = (i8)(int)q0; b[k] = (i8)(int)q1; c[k] = (i8)(int)q2;
    }
    *(i8x4*)(p0 + i) = a; *(i8x4*)(p1 + i) = b; *(i8x4*)(p2 + i) = c;
}

DEVFN void spliti8_2(const float* src, i8* p0, i8* p1, int i) {
    float4 v = *(const float4*)(src + i);
    float vv[4] = {v.x, v.y, v.z, v.w};
    i8x4 a, b;
#pragma unroll
    for (int k = 0; k < 4; ++k) {
        float t  = vv[k] * 4096.0f;
        float q0 = rintf(t);  float r = t - q0;
        float q1 = rintf(r * 128.0f);
        a[k] = (i8)(int)q0; b[k] = (i8)(int)q1;
    }
    *(i8x4*)(p0 + i) = a; *(i8x4*)(p1 + i) = b;
}

static constexpr int SB_W0 = 2048;
static constexpr int SB_W1 = 4096;
static constexpr int SB_W2 = 2048;
static constexpr int SB_X  = 6400;

__global__ void split_all(const float* __restrict__ w0, bf16* w0p0, bf16* w0p1, bf16* w0p2,
                          const float* __restrict__ w1, i8* w1q0, i8* w1q1, i8* w1q2,
                          const float* __restrict__ w2, i8* w2q0, i8* w2q1,
                          const float* __restrict__ x,  bf16* xp0,  bf16* xp1,  bf16* xp2) {
    int b = blockIdx.x;
    if (b < SB_W0) {
        split3_chunk(w0, w0p0, w0p1, w0p2, b * 1024 + threadIdx.x * 4);
    } else if (b < SB_W0 + SB_W1) {
        spliti8_3(w1, w1q0, w1q1, w1q2, (b - SB_W0) * 1024 + threadIdx.x * 4);
    } else if (b < SB_W0 + SB_W1 + SB_W2) {
        spliti8_2(w2, w2q0, w2q1, (b - SB_W0 - SB_W1) * 1024 + threadIdx.x * 4);
    } else {
        split3_chunk(x, xp0, xp1, xp2, (b - SB_W0 - SB_W1 - SB_W2) * 1024 + threadIdx.x * 4);
    }
}

// ---------------------------------------------------------------------------
// L0 GEMM: unchanged R6 structure (bf16 16x16x32, BK=32, 6 passes, dual f32
// acc, single __syncthreads per K-tile, 1-body prefetch, wave-pair stagger).
DEVFN void mfma16(f32x4 (&acc)[4][4], const bf16x8* a, const bf16x8* b) {
    __builtin_amdgcn_s_setprio(1);
#pragma unroll
    for (int i = 0; i < 4; ++i)
#pragma unroll
        for (int j = 0; j < 4; ++j)
            acc[i][j] = __builtin_amdgcn_mfma_f32_16x16x32_bf16(a[i], b[j], acc[i][j], 0, 0, 0);
    __builtin_amdgcn_s_setprio(0);
}

DEVFN void frag4b(bf16x8* f, const bf16* s, int wrow, int fr, int fkS) {
#pragma unroll
    for (int i = 0; i < 4; ++i)
        f[i] = *(const bf16x8*)((const char*)s + (wrow + i * 16 + fr) * 64 + fkS);
}

__global__ __launch_bounds__(512, 2)
void gemm_l0(const bf16* __restrict__ A0, const bf16* __restrict__ A1,
             const bf16* __restrict__ A2, const bf16* __restrict__ B0,
             const bf16* __restrict__ B1, const bf16* __restrict__ B2,
             const float* __restrict__ bias, float* __restrict__ C,
             int M, int N, int K) {
    constexpr int APL = 256 * 32;            // A plane elems (16 KiB)
    constexpr int BPL = 128 * 32;            // B plane elems ( 8 KiB)
    constexpr int BUF = 3 * APL + 3 * BPL;
    __shared__ __align__(1024) bf16 lds[2 * BUF];   // 144 KiB

    const int t = threadIdx.x, lane = t & 63, wv = t >> 6;
    const int wm = (wv >> 1) * 64, wn = (wv & 1) * 64;
    const int bm = blockIdx.x * 256, bn = blockIdx.y * 128;
    const int sk = (wv >> 2) & 1;            // SIMD-partner stagger key
    const int fr = lane & 15, g = lane >> 4;
    const int fkS = (g ^ ((lane >> 1) & 3)) * 16;
    const int cr = g * 4, cc = fr;

    f32x4 accM[4][4] = {}, accS[4][4] = {};

    auto pA = [&](int p, int i) { return lds + p * BUF + i * APL; };
    auto pB = [&](int p, int i) { return lds + p * BUF + 3 * APL + i * BPL; };

    int offA[2], offB[1];
#pragma unroll
    for (int r = 0; r < 2; ++r) {
        int c = t + r * 512, row = c >> 2, slot = c & 3;
        offA[r] = (bm + row) * K + (slot ^ ((row >> 1) & 3)) * 8;
    }
    {
        int c = t, row = c >> 2, slot = c & 3;
        offB[0] = (bn + row) * K + (slot ^ ((row >> 1) & 3)) * 8;
    }
    auto stA = [&](const bf16* gp, bf16* s, int k0) {
#pragma unroll
        for (int r = 0; r < 2; ++r)
            llds16(gp + offA[r] + k0, (char*)s + ((t + r * 512) >> 6) * 1024);
    };
    auto stB = [&](const bf16* gp, bf16* s, int k0) {
        llds16(gp + offB[0] + k0, (char*)s + (t >> 6) * 1024);
    };

    stA(A0, pA(0, 0), 0); stA(A1, pA(0, 1), 0); stA(A2, pA(0, 2), 0);
    stB(B0, pB(0, 0), 0); stB(B1, pB(0, 1), 0); stB(B2, pB(0, 2), 0);
    __syncthreads();

    const int NT = K / 32;
    int p = 0;
    for (int tt = 0; tt < NT; ++tt, p ^= 1) {
        const int q = p ^ 1, kn = (tt + 1) * 32;
        const bool pf = (tt + 1 < NT);
        bf16x8 a[4], b0f[4], b1f[4], b2f[4];
        if (sk == 0) {
            frag4b(a,   pA(p, 0), wm, fr, fkS);
            frag4b(b0f, pB(p, 0), wn, fr, fkS);
            if (pf) stA(A0, pA(q, 0), kn);
            mfma16(accM, a, b0f);                        // a0b0
            if (pf) { stA(A1, pA(q, 1), kn); stA(A2, pA(q, 2), kn); }
            frag4b(b1f, pB(p, 1), wn, fr, fkS);
            mfma16(accS, a, b1f);                        // a0b1
            if (pf) { stB(B0, pB(q, 0), kn); stB(B1, pB(q, 1), kn); stB(B2, pB(q, 2), kn); }
            frag4b(b2f, pB(p, 2), wn, fr, fkS);
            mfma16(accS, a, b2f);                        // a0b2
            frag4b(a, pA(p, 1), wm, fr, fkS);
            mfma16(accS, a, b0f);                        // a1b0
            mfma16(accS, a, b1f);                        // a1b1
            frag4b(a, pA(p, 2), wm, fr, fkS);
            mfma16(accS, a, b0f);                        // a2b0
        } else {
            frag4b(a,   pA(p, 1), wm, fr, fkS);          // a1
            frag4b(b0f, pB(p, 0), wn, fr, fkS);
            if (pf) stA(A0, pA(q, 0), kn);
            mfma16(accS, a, b0f);                        // a1b0
            if (pf) { stA(A1, pA(q, 1), kn); stA(A2, pA(q, 2), kn); }
            frag4b(b1f, pB(p, 1), wn, fr, fkS);
            mfma16(accS, a, b1f);                        // a1b1
            if (pf) { stB(B0, pB(q, 0), kn); stB(B1, pB(q, 1), kn); stB(B2, pB(q, 2), kn); }
            frag4b(a, pA(p, 2), wm, fr, fkS);
            mfma16(accS, a, b0f);                        // a2b0
            frag4b(a, pA(p, 0), wm, fr, fkS);            // a0
            mfma16(accM, a, b0f);                        // a0b0
            frag4b(b2f, pB(p, 2), wn, fr, fkS);
            mfma16(accS, a, b1f);                        // a0b1
            mfma16(accS, a, b2f);                        // a0b2
        }
        __syncthreads();
    }

#pragma unroll
    for (int j = 0; j < 4; ++j) {
        int col = bn + wn + j * 16 + cc;
        double bvs = (double)bias[col];
#pragma unroll
        for (int i = 0; i < 4; ++i) {
            int row0 = bm + wm + i * 16 + cr;
#pragma unroll
            for (int r = 0; r < 4; ++r) {
                double v = (double)accM[i][j][r] + (double)accS[i][j][r] + bvs;
                C[(size_t)(row0 + r) * N + col] = (float)v;
            }
        }
    }
}

// ---------------------------------------------------------------------------
// NEW: i8 GEMM for L1/L2. A = spikes {0,1} exact i8; B = base-128 digit
// planes. mfma_i32_16x16x64_i8 (2x bf16 rate, exact i32 acc). BK=128 i8 =
// 128B rows -> staging/read swizzle byte-identical to the verified bf16-BK=64
// pattern (slot = chunk ^ (row&7); read chunk (kh*4+g)^(lane&7); 0 conflicts).
// K-order inside the MFMA is permutation-safe: A and B use the same assumed
// byte->k map, so any HW k-permutation cancels in the contraction.
// MODE 1 (L1): 3 planes, 3 i32 accs -> wave tile 64x32 (96 acc regs) to stay
// in the 2-waves/SIMD register bucket; block 256x64.
// MODE 2 (L2): 2 planes, wave tile 64x64 (128 acc regs, same as bf16 dual).
template <int MODE>
__global__ __launch_bounds__(512, 2)
void gemm_i8(const i8* __restrict__ A, const i8* __restrict__ B0,
             const i8* __restrict__ B1, const i8* __restrict__ B2,
             const float* __restrict__ bias, float* __restrict__ C,
             int M, int N, int K) {
    constexpr int NP  = (MODE == 1) ? 3 : 2;
    constexpr int BN  = (MODE == 1) ? 64 : 128;
    constexpr int WNF = (MODE == 1) ? 2 : 4;     // 16-col frags per wave
    constexpr int BK  = 128;
    constexpr int APL = 256 * BK;                // bytes
    constexpr int BPL = BN * BK;
    constexpr int BUF = APL + NP * BPL;          // L1 56K, L2 64K
    constexpr int AIT = 4;                       // 2048 chunks / 512 thr
    constexpr int BIT = (BN * 8) / 512;          // 1 or 2
    __shared__ __align__(1024) i8 lds[2 * BUF];  // 112K / 128K

    const int t = threadIdx.x, lane = t & 63, wv = t >> 6;
    const int wm = (wv >> 1) * 64, wn = (wv & 1) * (WNF * 16);
    const int bm = blockIdx.x * 256, bn = blockIdx.y * BN;
    const int fr = lane & 15, g = lane >> 4;
    const int fkA = (g ^ (lane & 7)) * 16;       // k-half 0 chunk, bytes
    const int fkB = ((4 + g) ^ (lane & 7)) * 16; // k-half 1
    const int cr = g * 4, cc = fr;

    i32x4 acc[NP][4][WNF] = {};

    int offA[AIT], offB[BIT];
#pragma unroll
    for (int r = 0; r < AIT; ++r) {
        int c = t + r * 512, row = c >> 3, slot = c & 7;
        offA[r] = (bm + row) * K + (slot ^ (row & 7)) * 16;
    }
#pragma unroll
    for (int r = 0; r < BIT; ++r) {
        int c = t + r * 512, row = c >> 3, slot = c & 7;
        offB[r] = (bn + row) * K + (slot ^ (row & 7)) * 16;
    }
    auto stA = [&](const i8* gp, i8* s, int k0) {
#pragma unroll
        for (int r = 0; r < AIT; ++r)
            llds16(gp + offA[r] + k0, s + ((t + r * 512) >> 6) * 1024);
    };
    auto stB = [&](const i8* gp, i8* s, int k0) {
#pragma unroll
        for (int r = 0; r < BIT; ++r)
            llds16(gp + offB[r] + k0, s + ((t + r * 512) >> 6) * 1024);
    };
    auto pAl = [&](int p) { return lds + p * BUF; };
    auto pBl = [&](int p, int pl) { return lds + p * BUF + APL + pl * BPL; };

    stA(A, pAl(0), 0);
    stB(B0, pBl(0, 0), 0);
    stB(B1, pBl(0, 1), 0);
    if constexpr (NP == 3) stB(B2, pBl(0, 2), 0);
    __syncthreads();

    const int NT = K / BK;
    int p = 0;
    for (int tt = 0; tt < NT; ++tt, p ^= 1) {
        const int q = p ^ 1, kn = (tt + 1) * BK;
        const bool pf = (tt + 1 < NT);
        const i8* sA = pAl(p);
        i32x4 av[4], bvf[NP][WNF];
#pragma unroll
        for (int kh = 0; kh < 2; ++kh) {
            const int fk = kh ? fkB : fkA;
#pragma unroll
            for (int i = 0; i < 4; ++i)
                av[i] = *(const i32x4*)(sA + (wm + i * 16 + fr) * 128 + fk);
            if (kh == 0 && pf) stA(A, pAl(q), kn);
#pragma unroll
            for (int pl = 0; pl < NP; ++pl) {
                const i8* sB = pBl(p, pl);
#pragma unroll
                for (int j = 0; j < WNF; ++j)
                    bvf[pl][j] = *(const i32x4*)(sB + (wn + j * 16 + fr) * 128 + fk);
            }
            if (kh == 0 && pf) {
                stB(B0, pBl(q, 0), kn);
                stB(B1, pBl(q, 1), kn);
                if constexpr (NP == 3) stB(B2, pBl(q, 2), kn);
            }
            __builtin_amdgcn_s_setprio(1);
#pragma unroll
            for (int pl = 0; pl < NP; ++pl)
#pragma unroll
                for (int i = 0; i < 4; ++i)
#pragma unroll
                    for (int j = 0; j < WNF; ++j)
                        acc[pl][i][j] = __builtin_amdgcn_mfma_i32_16x16x64_i8(
                            av[i], bvf[pl][j], acc[pl][i][j], 0, 0, 0);
            __builtin_amdgcn_s_setprio(0);
        }
        __syncthreads();
    }

    // exact integer dots merged in fp64: cur = (d0 + d1/128 [+ d2/16384])/4096 + b
#pragma unroll
    for (int j = 0; j < WNF; ++j) {
        int col = bn + wn + j * 16 + cc;
        double bvs = (double)bias[col];
#pragma unroll
        for (int i = 0; i < 4; ++i) {
            int row0 = bm + wm + i * 16 + cr;
#pragma unroll
            for (int r = 0; r < 4; ++r) {
                double v = (double)acc[0][i][j][r] + (double)acc[1][i][j][r] * (1.0 / 128.0);
                if constexpr (NP == 3) v += (double)acc[2][i][j][r] * (1.0 / 16384.0);
                C[(size_t)(row0 + r) * N + col] = (float)(v * (1.0 / 4096.0) + bvs);
            }
        }
    }
}

// ---------------------------------------------------------------------------
// LIF scans — fp64 recurrence (verified). Hidden spikes now emitted as i8
// {0,1} (exact either way; feeds the i8 GEMMs).
template <int F>
__global__ void lif_hidden(const float* __restrict__ cur, i8* __restrict__ spk) {
    const int tid = blockIdx.x * 256 + threadIdx.x;  // b*F + f
    double m = 0.0;
    size_t off = tid;
#pragma unroll
    for (int t = 0; t < T_STEPS; ++t) {
        m = 0.9 * m + (double)cur[off];
        bool s = (m - 1.0) > 0.0;
        spk[off] = s ? (i8)1 : (i8)0;
        if (s) m -= 1.0;
        off += (size_t)BATCH * F;
    }
}

__global__ void lif_out(const float* __restrict__ cur, float* __restrict__ out) {
    const int tid = blockIdx.x * 256 + threadIdx.x;  // b*1024 + f
    double m = 0.0;
    size_t off = tid;
#pragma unroll
    for (int t = 0; t < T_STEPS; ++t) {
        m = 0.9 * m + (double)cur[off];
        bool s = (m - 1.0) > 0.0;
        out[off] = s ? 1.0f : 0.0f;
        if (s) m -= 1.0;
        off += (size_t)BATCH * 1024;
    }
    out[(size_t)T_STEPS * BATCH * 1024 + tid] = (float)m;  // final membrane (output 1)
}

// ---------------------------------------------------------------------------
extern "C" void kernel_launch(void* const* d_in, const int* in_sizes, int n_in,
                              void* d_out, int out_size, void* d_ws, size_t ws_size,
                              hipStream_t stream) {
    const float* xin = (const float*)d_in[0];
    const float* w0  = (const float*)d_in[1];
    const float* b0  = (const float*)d_in[2];
    const float* w1  = (const float*)d_in[3];
    const float* b1  = (const float*)d_in[4];
    const float* w2  = (const float*)d_in[5];
    const float* b2  = (const float*)d_in[6];
    float* out = (float*)d_out;

    constexpr size_t NW0 = 2048 * 1024;
    constexpr size_t NW1 = 2048 * 2048;
    constexpr size_t NW2 = 1024 * 2048;
    constexpr size_t NX  = (size_t)MROWS * 1024;  // 6,553,600
    constexpr size_t NH  = (size_t)MROWS * 2048;  // 13,107,200

    char* ws = (char*)d_ws;
    size_t off = 0;
    auto carve = [&](size_t bytes) { char* p = ws + off; off += bytes; return p; };

    // long-lived planes: w1 -> 3 i8 digit planes, w2 -> 2
    i8* w1q0 = (i8*)carve(NW1);
    i8* w1q1 = (i8*)carve(NW1);
    i8* w1q2 = (i8*)carve(NW1);
    i8* w2q0 = (i8*)carve(NW2);
    i8* w2q1 = (i8*)carve(NW2);
    // pool: w0 bf16 planes + x bf16 planes live only until G0; s0/s1 (i8) after
    char* pool = carve(2 * NH * 2);          // 52,428,800 B
    bf16* w0p0 = (bf16*)pool;
    bf16* w0p1 = w0p0 + NW0;
    bf16* w0p2 = w0p1 + NW0;
    bf16* xp0  = w0p2 + NW0;
    bf16* xp1  = xp0 + NX;
    bf16* xp2  = xp1 + NX;                   // ends at pool + 51,904,512
    i8* s0 = (i8*)pool;                      // written after G0 consumed w0/x
    i8* s1 = s0 + NH;
    float* cur = (float*)carve(NH * 4);
    if (ws_size < off) return;               // ~121 MB total

    // 1) fused precision splits (one launch)
    split_all<<<SB_W0 + SB_W1 + SB_W2 + SB_X, 256, 0, stream>>>(
        w0, w0p0, w0p1, w0p2, w1, w1q0, w1q1, w1q2,
        w2, w2q0, w2q1, xin, xp0, xp1, xp2);

    // 2) layer 0: cur0 = x @ W0^T + b0 (bf16 6-pass dual-acc, unchanged)
    gemm_l0<<<dim3(25, 16), 512, 0, stream>>>(xp0, xp1, xp2, w0p0, w0p1, w0p2,
                                              b0, cur, MROWS, 2048, 1024);
    lif_hidden<2048><<<(BATCH * 2048) / 256, 256, 0, stream>>>(cur, s0);

    // 3) layer 1: cur1 = s0 @ W1^T + b1 (i8 3-plane, exact i32 acc)
    gemm_i8<1><<<dim3(25, 32), 512, 0, stream>>>(s0, w1q0, w1q1, w1q2,
                                                 b1, cur, MROWS, 2048, 2048);
    lif_hidden<2048><<<(BATCH * 2048) / 256, 256, 0, stream>>>(cur, s1);

    // 4) layer 2: cur2 = s1 @ W2^T + b2 (i8 2-plane)
    gemm_i8<2><<<dim3(25, 8), 512, 0, stream>>>(s1, w2q0, w2q1, nullptr,
                                                b2, cur, MROWS, 1024, 2048);
    lif_out<<<(BATCH * 1024) / 256, 256, 0, stream>>>(cur, out);
}